// Round 5
// baseline (293.162 us; speedup 1.0000x reference)
//
#include <hip/hip_runtime.h>

// Broadcast helpers via v_readlane (uniform SGPR result).
__device__ __forceinline__ int rdlane_i(int v, int l) {
    return __builtin_amdgcn_readlane(v, l);
}
__device__ __forceinline__ float rdlane_f(float v, int l) {
    return __int_as_float(__builtin_amdgcn_readlane(__float_as_int(v), l));
}

// One butterfly step of a 64-lane INTEGER max (order-equivalent to float
// max for our keys: alive keys are non-negative floats, dead keys are
// -inf-packed => hugely negative ints; bound_ctrl injects 0 which never
// beats a real alive key).
template <int CTRL>
__device__ __forceinline__ int dpp_imax_step(int x) {
    int t = __builtin_amdgcn_update_dpp(0, x, CTRL, 0xF, 0xF, true);
    return (t > x) ? t : x;
}

// Full 64-lane int max; result valid in lane 63.
__device__ __forceinline__ int wave_imax_to_lane63(int x) {
    x = dpp_imax_step<0xB1>(x);   // xor 1
    x = dpp_imax_step<0x4E>(x);   // xor 2
    x = dpp_imax_step<0x141>(x);  // row_half_mirror (xor within 8)
    x = dpp_imax_step<0x140>(x);  // row_mirror      (xor within 16)
    x = dpp_imax_step<0x142>(x);  // row_bcast15     (16 -> 32)
    x = dpp_imax_step<0x143>(x);  // row_bcast31     (32 -> 64)
    return x;
}

// One wave = one 64x64 matrix, lane i owns ROW i in registers A[0..63].
// Block = 128 threads: wave 0 -> spin-up matrix, wave 1 -> spin-dn matrix.
//
// REGISTER-ALLOCATION HISTORY (the whole game on this kernel):
//   R0/R1 (default):        arch VGPR 36, dur 243us  -> A[64] in AGPRs
//   R2 (waves_per_eu(4,4)): arch VGPR 52, dur 243us  -> still AGPRs
//   R3 (2-wave, A[32]):     arch VGPR 24, dur 266us  -> still AGPRs
//   R4 ((2,4) + "+v" asm):  arch VGPR 52, dur 242us  -> STILL AGPRs; the
//       "+v" constraint only forces a VGPR at the asm site, so the
//       allocator homes A[] in AGPRs and wraps every asm in
//       v_accvgpr_read/write: 4 VALU ops per update element instead of 2
//       (measured ~16K instr/wave vs ~6K floor, VALUBusy ~90%, pure
//       issue-bound: occupancy 25..83% never moved duration).
// Root cause: the allocator budgets registers for the MAX waves/EU target
// (4 -> 128 unified -> ~64-reg arch share); our ~92-reg working set
// overflows the arch share and spills to AGPR. Fix: waves_per_eu(2,2)
// makes the budget 256/wave -> arch share >= 128 > 92 -> A[64] lives in
// arch VGPRs, zero cross-file moves. 2 waves/SIMD is plenty: the update
// has 63 independent readlane->fmac chains per step (ILP-rich).
__global__ __launch_bounds__(128)
__attribute__((amdgpu_waves_per_eu(2, 2)))
void slater_logdet_kernel(
        const float* __restrict__ rs, const float* __restrict__ log_alpha_p,
        float* __restrict__ out) {
    const int b    = blockIdx.x;
    const int tid  = threadIdx.x;
    const int wave = tid >> 6;   // 0 = up, 1 = dn
    const int lane = tid & 63;

    const float Lbox = 10.0f;
    const float PI_F = 3.14159265358979323846f;

    float alpha = __expf(log_alpha_p[0]);
    alpha = fminf(fmaxf(alpha, 0.5f / (Lbox * Lbox)), 200.0f / (Lbox * Lbox));

    // Electron position for this lane (row index = electron index).
    const float* rp = rs + (size_t)b * 384 + (size_t)(wave * 64 + lane) * 3;
    float x = rp[0], y = rp[1], z = rp[2];

    float sx, cx, sy, cy, sz, cz;
    __sincosf(x * (PI_F / Lbox), &sx, &cx);
    __sincosf(y * (PI_F / Lbox), &sy, &cy);
    __sincosf(z * (PI_F / Lbox), &sz, &cz);

    // Separable build: Phi[i][j] = ex[mx]*ey[my]*ez[mz], j = mx*16+my*4+mz.
    // Only 12 exps + ~80 muls per lane (vs 64 exps in the column layout).
    const float off = wave ? 0.5f : 0.0f;
    const float LPI = Lbox / PI_F;
    float ex[4], ey[4], ez[4];
#pragma unroll
    for (int m = 0; m < 4; ++m) {
        float sp, cp;
        __sincosf((PI_F * 0.25f) * ((float)m + off), &sp, &cp);
        float dx = LPI * (sx * cp - cx * sp);
        float dy = LPI * (sy * cp - cy * sp);
        float dz = LPI * (sz * cp - cz * sp);
        ex[m] = __expf(-alpha * dx * dx);
        ey[m] = __expf(-alpha * dy * dy);
        ez[m] = __expf(-alpha * dz * dz);
    }
    float exy[16];
#pragma unroll
    for (int q = 0; q < 16; ++q) exy[q] = ex[q >> 2] * ey[q & 3];
    float A[64];
#pragma unroll
    for (int j = 0; j < 64; ++j) A[j] = exy[j >> 2] * ez[j & 3];

    // LU with partial pivoting, row-owner layout, NO physical row swap:
    // pivot rows stay in their lane; flag = -inf marks them dead so the
    // argmax never selects them again. det sign is irrelevant (log|det|).
    //
    // Pivot search: pack the lane index into the low 6 bits of the key's
    // mantissa and take an integer max — the winning lane index falls out
    // of the max result itself (no ballot/ffs).
    float flag   = 0.0f;   // 0 while alive, -inf once used as pivot row
    float logdet = 0.0f;
#pragma unroll
    for (int k = 0; k < 64; ++k) {
        // key = |A[k]| for alive rows, -inf for dead rows (one v_add w/ |mod|)
        float key = fabsf(A[k]) + flag;
        int   ki  = (__float_as_int(key) & ~63) | lane;  // keep sign bit!
        int   g   = rdlane_i(wave_imax_to_lane63(ki), 63);
        int   p   = g & 63;                        // pivot row's physical lane

        float pv  = rdlane_f(A[k], p);
        float inv = __builtin_amdgcn_rcpf(pv);
        inv = inv * (2.0f - pv * inv);             // 1 Newton step (~0.5 ulp)
        logdet += __logf(fabsf(pv));

        // Mark pivot row dead for future argmaxes.
        flag = (lane == p) ? -__builtin_huge_valf() : flag;

        // One multiplier per lane; lane p gets m~=1 and self-annihilates
        // (its row is never read again), dead lanes have A[k]=~0.
        float m  = A[k] * inv;
        float nm = -m;

        // Rank-1 update, 2 VALU ops per element once A[] is architectural:
        //   v_readlane_b32 sS, vA[j], sP   (pivot-row elem -> SGPR)
        //   v_fmac_f32     vA[j], sS, vNM  (A[j] += (-m) * s; src0=SGPR ok)
#pragma unroll
        for (int j = k + 1; j < 64; ++j) {
            float s_tmp;
            asm("v_readlane_b32 %1, %0, %3\n\t"
                "v_fmac_f32 %0, %1, %2"
                : "+v"(A[j]), "=&s"(s_tmp)
                : "v"(nm), "s"(p));
        }
    }

    // logdet is lane-uniform. Combine the two spins.
    __shared__ float partial[2];
    if (lane == 0) partial[wave] = logdet;
    __syncthreads();
    if (tid == 0) out[b] = partial[0] + partial[1];
}

extern "C" void kernel_launch(void* const* d_in, const int* in_sizes, int n_in,
                              void* d_out, int out_size, void* d_ws, size_t ws_size,
                              hipStream_t stream) {
    const float* rs = (const float*)d_in[0];
    const float* la = (const float*)d_in[1];
    float* out      = (float*)d_out;
    slater_logdet_kernel<<<out_size, 128, 0, stream>>>(rs, la, out);
}